// Round 8
// baseline (211.335 us; speedup 1.0000x reference)
//
#include <hip/hip_runtime.h>
#include <stdint.h>
#include <math.h>

// Problem: B=4, S=2048, E=1024, H=16, D=64
// d_in order (setup_inputs dict): x, Wk, Wq, Wv, Wu, bu   (note Wk before Wq!)

typedef __attribute__((ext_vector_type(8))) short bf16x8;
typedef __attribute__((ext_vector_type(4))) float f32x4;
typedef __attribute__((ext_vector_type(16))) float f32x16;
typedef __attribute__((ext_vector_type(4))) int i32x4;
typedef __attribute__((ext_vector_type(4))) short s16x4;

#define GLOAD_LDS16(gp, lp)                                                     \
  __builtin_amdgcn_global_load_lds(                                             \
      (__attribute__((address_space(1))) void*)(gp),                            \
      (__attribute__((address_space(3))) void*)(lp), 16, 0, 0)

#define WAITVM(N) asm volatile("s_waitcnt vmcnt(" #N ")" ::: "memory")

__device__ __forceinline__ short f2bf(float f) {
  union { float f; uint32_t u; } v; v.f = f;
  uint32_t r = v.u + 0x7FFFu + ((v.u >> 16) & 1u);  // RNE
  return (short)(r >> 16);
}
__device__ __forceinline__ float bf2f(short s) {
  union { uint32_t u; float f; } v; v.u = ((uint32_t)(uint16_t)s) << 16;
  return v.f;
}
__device__ __forceinline__ short f2bfn(float f) {
  union { __bf16 h; short s; } u; u.h = (__bf16)f; return u.s;
}
__device__ __forceinline__ uint32_t pk2n(float a, float b) {
  union { __bf16 h[2]; uint32_t u; } v;
  v.h[0] = (__bf16)a; v.h[1] = (__bf16)b;
  return v.u;
}

// exchange across the lane<32 / lane>=32 split (T12)
__device__ __forceinline__ void swap32(uint32_t a, uint32_t b, int hi,
                                       uint32_t& out0, uint32_t& out1) {
#if __has_builtin(__builtin_amdgcn_permlane32_swap)
  typedef __attribute__((ext_vector_type(2))) int i32x2;
  i32x2 r = __builtin_amdgcn_permlane32_swap((int)a, (int)b, false, false);
  out0 = (uint32_t)r.x; out1 = (uint32_t)r.y;
#else
  uint32_t ta = (uint32_t)__shfl_xor((int)a, 32);
  uint32_t tb = (uint32_t)__shfl_xor((int)b, 32);
  out0 = hi ? tb : a;
  out1 = hi ? b : ta;
#endif
}

// ---------------- cast fp32 -> bf16, vectorized (G13) ----------------
__global__ __launch_bounds__(256) void cast_kernel(const float* __restrict__ src,
                                                   short* __restrict__ dst, int n) {
  int i = (blockIdx.x * 256 + threadIdx.x) * 8;
  if (i >= n) return;
  const float4* s = (const float4*)(src + i);
  float4 f0 = s[0], f1 = s[1];
  bf16x8 o;
  o[0] = f2bf(f0.x); o[1] = f2bf(f0.y); o[2] = f2bf(f0.z); o[3] = f2bf(f0.w);
  o[4] = f2bf(f1.x); o[5] = f2bf(f1.y); o[6] = f2bf(f1.z); o[7] = f2bf(f1.w);
  *(bf16x8*)(dst + i) = o;
}

__global__ __launch_bounds__(256) void cast4_kernel(const float* __restrict__ w0,
                                                    const float* __restrict__ w1,
                                                    const float* __restrict__ w2,
                                                    const float* __restrict__ w3,
                                                    short* o0, short* o1, short* o2, short* o3) {
  const float* src = (blockIdx.y == 0) ? w0 : (blockIdx.y == 1) ? w1 : (blockIdx.y == 2) ? w2 : w3;
  short* dst = (blockIdx.y == 0) ? o0 : (blockIdx.y == 1) ? o1 : (blockIdx.y == 2) ? o2 : o3;
  int i = (blockIdx.x * 256 + threadIdx.x) * 8;
  const float4* s = (const float4*)(src + i);
  float4 f0 = s[0], f1 = s[1];
  bf16x8 o;
  o[0] = f2bf(f0.x); o[1] = f2bf(f0.y); o[2] = f2bf(f0.z); o[3] = f2bf(f0.w);
  o[4] = f2bf(f1.x); o[5] = f2bf(f1.y); o[6] = f2bf(f1.z); o[7] = f2bf(f1.w);
  *(bf16x8*)(dst + i) = o;
}

// ---------------- B^T GEMM (m97 structure): C[i,j] = sum_k A[i,k]*B[j,k] ----
template <bool F32OUT>
__device__ __forceinline__ void gemm_bt_core(const short* __restrict__ A,
                                             const short* __restrict__ Bm,
                                             short* __restrict__ Cb,
                                             float* __restrict__ Cf,
                                             const float* __restrict__ bias) {
  __shared__ short a_lds[128 * 64];
  __shared__ short b_lds[128 * 64];
  const int tid = threadIdx.x;
  const int w = tid >> 6, l = tid & 63;
  const int l15 = l & 15, lhi = l >> 4;
  const int wr = w >> 1, wc = w & 1;
  const int row0 = blockIdx.x * 128;
  const int col0 = blockIdx.y * 128;

  f32x4 acc[4][4];
#pragma unroll
  for (int m = 0; m < 4; ++m)
#pragma unroll
    for (int n = 0; n < 4; ++n)
      acc[m][n] = (f32x4){0.f, 0.f, 0.f, 0.f};

  const int o0 = tid * 16;
  const int sr = o0 >> 7;
  const int sc = o0 & 127;

  for (int kt = 0; kt < 16; ++kt) {
    const char* Ab = (const char*)A + (size_t)(row0 + sr) * 2048 + kt * 128 + sc;
    const char* Bb = (const char*)Bm + (size_t)(col0 + sr) * 2048 + kt * 128 + sc;
#pragma unroll
    for (int i = 0; i < 4; ++i) {
      GLOAD_LDS16(Ab + (size_t)i * 32 * 2048, (char*)a_lds + i * 4096 + o0);
      GLOAD_LDS16(Bb + (size_t)i * 32 * 2048, (char*)b_lds + i * 4096 + o0);
    }
    __syncthreads();
#pragma unroll
    for (int kk = 0; kk < 2; ++kk) {
      bf16x8 af[4], bg[4];
#pragma unroll
      for (int m = 0; m < 4; ++m) {
        int r = wr * 64 + m * 16 + l15;
        af[m] = *(const bf16x8*)((const char*)a_lds + r * 128 + kk * 64 + lhi * 16);
      }
#pragma unroll
      for (int n = 0; n < 4; ++n) {
        int r = wc * 64 + n * 16 + l15;
        bg[n] = *(const bf16x8*)((const char*)b_lds + r * 128 + kk * 64 + lhi * 16);
      }
#pragma unroll
      for (int m = 0; m < 4; ++m)
#pragma unroll
        for (int n = 0; n < 4; ++n)
          acc[m][n] = __builtin_amdgcn_mfma_f32_16x16x32_bf16(af[m], bg[n], acc[m][n], 0, 0, 0);
    }
    __syncthreads();
  }

#pragma unroll
  for (int m = 0; m < 4; ++m) {
#pragma unroll
    for (int n = 0; n < 4; ++n) {
      int colg = col0 + wc * 64 + n * 16 + l15;
#pragma unroll
      for (int r = 0; r < 4; ++r) {
        int rowg = row0 + wr * 64 + m * 16 + lhi * 4 + r;
        float v = acc[m][n][r];
        if constexpr (F32OUT) {
          Cf[(size_t)rowg * 1024 + colg] = v + bias[colg];
        } else {
          Cb[(size_t)rowg * 1024 + colg] = f2bfn(v);
        }
      }
    }
  }
}

__global__ __launch_bounds__(256) void gemm_qkv_kernel(const short* __restrict__ xb,
                                                       const short* __restrict__ wq,
                                                       const short* __restrict__ wk,
                                                       const short* __restrict__ wv,
                                                       short* qo, short* ko, short* vo) {
  const short* Bm = (blockIdx.z == 0) ? wq : (blockIdx.z == 1) ? wk : wv;
  short* C = (blockIdx.z == 0) ? qo : (blockIdx.z == 1) ? ko : vo;
  gemm_bt_core<false>(xb, Bm, C, nullptr, nullptr);
}

__global__ __launch_bounds__(256) void gemm_out_kernel(const short* __restrict__ ob,
                                                       const short* __restrict__ wu,
                                                       const float* __restrict__ bias,
                                                       float* __restrict__ out) {
  gemm_bt_core<true>(ob, wu, nullptr, out, bias);
}

// ---------------- fragmentize Q,K: [bh][t32][s][lane][8] -------------------
// value = M[b][t*32 + (l&31)][h][(l>>5)*8 + s*16 + j]
__global__ __launch_bounds__(256) void frag_qk_kernel(const short* __restrict__ qb,
                                                      const short* __restrict__ kb,
                                                      short* __restrict__ qf,
                                                      short* __restrict__ kf) {
  int t = blockIdx.x, bh = blockIdx.y;
  int b = bh >> 4, h = bh & 15;
  __shared__ short q_t[32][72], k_t[32][72];
  int tid = threadIdx.x;
  int row = tid >> 3, seg = tid & 7;
  size_t src = ((size_t)(b * 2048 + t * 32 + row)) * 1024 + h * 64 + seg * 8;
  *(bf16x8*)&q_t[row][seg * 8] = *(const bf16x8*)(qb + src);
  *(bf16x8*)&k_t[row][seg * 8] = *(const bf16x8*)(kb + src);
  __syncthreads();
  int s = tid >> 6, l = tid & 63, l31 = l & 31, hi = l >> 5;
  bf16x8 cq = *(const bf16x8*)&q_t[l31][hi * 8 + s * 16];
  bf16x8 ck = *(const bf16x8*)&k_t[l31][hi * 8 + s * 16];
  size_t dst = ((size_t)bh * 64 + t) * 2048 + s * 512 + l * 8;
  *(bf16x8*)(qf + dst) = cq;
  *(bf16x8*)(kf + dst) = ck;
}

// ---------------- fragmentize V (transposed): [bh][t32][u][lane][8] --------
// u = dblk*2 + koff; value = V[b][t*32 + koff*16 + (l>>5)*8 + j][h][dblk*32 + (l&31)]
__global__ __launch_bounds__(256) void frag_v_kernel(const short* __restrict__ vb,
                                                     short* __restrict__ vf) {
  int t = blockIdx.x, bh = blockIdx.y;
  int b = bh >> 4, h = bh & 15;
  __shared__ short v_t[32][72];
  int tid = threadIdx.x;
  int row = tid >> 3, seg = tid & 7;
  *(bf16x8*)&v_t[row][seg * 8] =
      *(const bf16x8*)(vb + ((size_t)(b * 2048 + t * 32 + row)) * 1024 + h * 64 + seg * 8);
  __syncthreads();
  int u = tid >> 6, l = tid & 63, l31 = l & 31, hi = l >> 5;
  int dblk = u >> 1, koff = u & 1;
  bf16x8 c;
#pragma unroll
  for (int j = 0; j < 8; ++j) c[j] = v_t[koff * 16 + hi * 8 + j][dblk * 32 + l31];
  *(bf16x8*)(vf + ((size_t)bh * 64 + t) * 2048 + u * 512 + l * 8) = c;
}

// ---------------- causal flash attention v8: frag layout + counted vmcnt ----
// grid 512 (= 8 pairs x 64 bh), 256 thr (4 waves). Block processes 128-row
// q-tile j then tile 15-j (equal 34 k-tiles total). K/V staged as fragments
// via global_load_lds (coalesced source, conflict-free ds_read), 2 buffers,
// 2-ahead prefetch, raw s_barrier + counted vmcnt(4) (T4 -- never drain to 0
// mid-loop). All blocks equal-duration; id%8 == bh%8 keeps a bh on one XCD.
__global__ __launch_bounds__(256) void attn_kernel(const short* __restrict__ qf,
                                                   const short* __restrict__ kf,
                                                   const short* __restrict__ vf,
                                                   short* __restrict__ ob) {
  const float QSCALE = 0.03125f * 1.44269504f;  // (E^-0.25)^2 * log2(e)
  const float THR = 11.5416f;                   // 8 * log2(e)
  int id = blockIdx.x;
  int p = id >> 6;             // pair index 0..7
  int bh = id & 63;
  int b = bh >> 4, h = bh & 15;
  int wid = threadIdx.x >> 6, l = threadIdx.x & 63;
  int l31 = l & 31, hi = l >> 5;
  int tid = threadIdx.x;

  __shared__ short kbuf[2][4096];  // 8KB per 64-k tile (2x t32 frag sets)
  __shared__ short vbuf[2][4096];

  const short* qfb = qf + (size_t)bh * 131072;
  const short* kfb = kf + (size_t)bh * 131072;
  const short* vfb = vf + (size_t)bh * 131072;

#define STAGE(t, bi) do {                                                  \
    const short* ks_ = kfb + (t) * 4096 + tid * 8;                         \
    const short* vs_ = vfb + (t) * 4096 + tid * 8;                         \
    GLOAD_LDS16(ks_,        (char*)&kbuf[bi][0] + tid * 16);               \
    GLOAD_LDS16(ks_ + 2048, (char*)&kbuf[bi][0] + 4096 + tid * 16);        \
    GLOAD_LDS16(vs_,        (char*)&vbuf[bi][0] + tid * 16);               \
    GLOAD_LDS16(vs_ + 2048, (char*)&vbuf[bi][0] + 4096 + tid * 16);        \
  } while (0)

#pragma unroll
  for (int part = 0; part < 2; ++part) {
    int j = part ? (15 - p) : p;   // 128-row q-tile index 0..15
    int qt = 4 * j + wid;          // 32-row strip index
    int qrow0 = qt * 32;
    int qg = qrow0 + l31;
    int qmax = qrow0 + 31;
    int nk = 2 * (j + 1);          // 64-k tiles (>= 2)

    // Q fragments (coalesced from qf), pre-scaled
    bf16x8 aq[4];
    {
      const short* qp = qfb + qt * 2048 + l * 8;
#pragma unroll
      for (int s = 0; s < 4; ++s) {
        bf16x8 t = *(const bf16x8*)(qp + s * 512);
#pragma unroll
        for (int jj = 0; jj < 8; ++jj) t[jj] = f2bfn(bf2f(t[jj]) * QSCALE);
        aq[s] = t;
      }
    }

    f32x16 o_lo = {}, o_hi = {};
    float mr = -INFINITY, lsum = 0.f;

    STAGE(0, 0);
    STAGE(1, 1);
    WAITVM(4);                       // tile 0 landed (tile 1 in flight)
    __builtin_amdgcn_s_barrier();
    __builtin_amdgcn_sched_barrier(0);

    for (int t = 0; t < nk; ++t) {
      int k0 = t * 64;
      int cur = t & 1;
      if (k0 <= qmax) {              // wave-uniform causal skip (no barriers inside)
        const char* kb_ = (const char*)&kbuf[cur][0];
        const char* vb_ = (const char*)&vbuf[cur][0];
        f32x16 st0 = {}, st1 = {};
#pragma unroll
        for (int s = 0; s < 4; ++s) {
          bf16x8 ak = *(const bf16x8*)(kb_ + (s * 64 + l) * 16);
          st0 = __builtin_amdgcn_mfma_f32_32x32x16_bf16(ak, aq[s], st0, 0, 0, 0);
        }
#pragma unroll
        for (int s = 0; s < 4; ++s) {
          bf16x8 ak = *(const bf16x8*)(kb_ + 4096 + (s * 64 + l) * 16);
          st1 = __builtin_amdgcn_mfma_f32_32x32x16_bf16(ak, aq[s], st1, 0, 0, 0);
        }

        if (k0 + 31 > qrow0) {
#pragma unroll
          for (int r = 0; r < 16; ++r) {
            int kk = k0 + (r & 3) + 8 * (r >> 2) + 4 * hi;
            if (kk > qg) st0[r] = -INFINITY;
          }
        }
        if (k0 + 63 > qrow0) {
#pragma unroll
          for (int r = 0; r < 16; ++r) {
            int kk = k0 + 32 + (r & 3) + 8 * (r >> 2) + 4 * hi;
            if (kk > qg) st1[r] = -INFINITY;
          }
        }

        // max tree (depth 5)
        float mx[16];
#pragma unroll
        for (int r = 0; r < 16; ++r) mx[r] = fmaxf(st0[r], st1[r]);
#pragma unroll
        for (int r = 0; r < 8; ++r) mx[r] = fmaxf(mx[r], mx[r + 8]);
#pragma unroll
        for (int r = 0; r < 4; ++r) mx[r] = fmaxf(mx[r], mx[r + 4]);
        float pmax = fmaxf(fmaxf(mx[0], mx[1]), fmaxf(mx[2], mx[3]));
        pmax = fmaxf(pmax, __shfl_xor(pmax, 32));

        if (pmax > mr + THR) {  // T13 defer-max
          float alpha = exp2f(mr - pmax);
          mr = pmax;
          lsum *= alpha;
#pragma unroll
          for (int r = 0; r < 16; ++r) { o_lo[r] *= alpha; o_hi[r] *= alpha; }
        }

#pragma unroll
        for (int r = 0; r < 16; ++r) st0[r] = exp2f(st0[r] - mr);
#pragma unroll
        for (int r = 0; r < 16; ++r) st1[r] = exp2f(st1[r] - mr);
        float sm[16];
#pragma unroll
        for (int r = 0; r < 16; ++r) sm[r] = st0[r] + st1[r];
#pragma unroll
        for (int r = 0; r < 8; ++r) sm[r] += sm[r + 8];
#pragma unroll
        for (int r = 0; r < 4; ++r) sm[r] += sm[r + 4];
        lsum += (sm[0] + sm[1]) + (sm[2] + sm[3]);

        // T12 pack: P -> bf16 A-fragments
        uint32_t a0, a2, b1, b3, c0, c2, d1, d3;
        swap32(pk2n(st0[0], st0[1]),   pk2n(st0[4], st0[5]),   hi, a0, a2);
        swap32(pk2n(st0[2], st0[3]),   pk2n(st0[6], st0[7]),   hi, b1, b3);
        swap32(pk2n(st0[8], st0[9]),   pk2n(st0[12], st0[13]), hi, c0, c2);
        swap32(pk2n(st0[10], st0[11]), pk2n(st0[14], st0[15]), hi, d1, d3);
        i32x4 u0 = {(int)a0, (int)b1, (int)a2, (int)b3};
        i32x4 u1 = {(int)c0, (int)d1, (int)c2, (int)d3};
        swap32(pk2n(st1[0], st1[1]),   pk2n(st1[4], st1[5]),   hi, a0, a2);
        swap32(pk2n(st1[2], st1[3]),   pk2n(st1[6], st1[7]),   hi, b1, b3);
        swap32(pk2n(st1[8], st1[9]),   pk2n(st1[12], st1[13]), hi, c0, c2);
        swap32(pk2n(st1[10], st1[11]), pk2n(st1[14], st1[15]), hi, d1, d3);
        i32x4 u2 = {(int)a0, (int)b1, (int)a2, (int)b3};
        i32x4 u3 = {(int)c0, (int)d1, (int)c2, (int)d3};
        bf16x8 pa0 = __builtin_bit_cast(bf16x8, u0);
        bf16x8 pa1 = __builtin_bit_cast(bf16x8, u1);
        bf16x8 pa2 = __builtin_bit_cast(bf16x8, u2);
        bf16x8 pa3 = __builtin_bit_cast(bf16x8, u3);

        // PV from V fragments (u = dblk*2 + koff; t2 sub-tile at +4096)
        bf16x8 av;
        av = *(const bf16x8*)(vb_ + (0 * 64 + l) * 16);           // t2=0 u=0
        o_lo = __builtin_amdgcn_mfma_f32_32x32x16_bf16(av, pa0, o_lo, 0, 0, 0);
        av = *(const bf16x8*)(vb_ + (1 * 64 + l) * 16);           // t2=0 u=1
        o_lo = __builtin_amdgcn_mfma_f32_32x32x16_bf16(av, pa1, o_lo, 0, 0, 0);
        av = *(const bf16x8*)(vb_ + 4096 + (0 * 64 + l) * 16);    // t2=1 u=0
        o_lo = __builtin_amdgcn_mfma_f32_32x32x16_bf16(av, pa2, o_lo, 0, 0, 0);
        av = *(const bf16x8*)(vb_ + 4096 + (1 * 64 + l) * 16);    // t2=1 u=1
        o_lo = __builtin_amdgcn_mfma_f32_32x32x16_bf16(av, pa3, o_lo, 0, 0, 0);
        av = *(const bf16x8*)(vb_ + (2 * 64 + l) * 16);           // t2=0 u=2
        o_hi = __builtin_amdgcn_mfma_f32_32x32x16_bf16(av, pa0, o_hi, 0, 0, 0);
        av = *(const bf16x8*)(vb_ + (3 * 64 + l) * 16);           // t2=0 u=3
        o_hi = __builtin_amdgcn_mfma_f32_32x32x16_bf16(av, pa1, o_hi, 0, 0, 0);
        av = *(const bf16x8*)(vb_ + 4096 + (2 * 64 + l) * 16);    // t2=1 u=2
        o_hi = __builtin_amdgcn_mfma_f32_32x32x16_bf16(av, pa2, o_hi, 0, 0, 0);
        av = *(const bf16x8*)(vb_ + 4096 + (3 * 64 + l) * 16);    // t2=1 u=3
        o_hi = __builtin_amdgcn_mfma_f32_32x32x16_bf16(av, pa3, o_hi, 0, 0, 0);
      }
      __builtin_amdgcn_s_barrier();          // all waves done reading buf[cur]
      __builtin_amdgcn_sched_barrier(0);
      if (t + 2 < nk) {
        STAGE(t + 2, cur);
        WAITVM(4);                           // tile t+1's loads complete
      } else {
        WAITVM(0);
      }
      __builtin_amdgcn_s_barrier();          // tile t+1 visible to all waves
      __builtin_amdgcn_sched_barrier(0);
    }

    lsum += __shfl_xor(lsum, 32);
    float inv = 1.0f / lsum;
    short* obase = ob + (size_t)(b * 2048 + qg) * 1024 + h * 64;
#pragma unroll
    for (int g = 0; g < 4; ++g) {
      int d0 = 8 * g + 4 * hi;
      s16x4 v0, v1;
#pragma unroll
      for (int jj = 0; jj < 4; ++jj) {
        v0[jj] = f2bfn(o_lo[4 * g + jj] * inv);
        v1[jj] = f2bfn(o_hi[4 * g + jj] * inv);
      }
      *(s16x4*)(obase + d0) = v0;
      *(s16x4*)(obase + 32 + d0) = v1;
    }
  }
#undef STAGE
}

extern "C" void kernel_launch(void* const* d_in, const int* in_sizes, int n_in,
                              void* d_out, int out_size, void* d_ws, size_t ws_size,
                              hipStream_t stream) {
  const float* x  = (const float*)d_in[0];
  const float* Wk = (const float*)d_in[1];
  const float* Wq = (const float*)d_in[2];
  const float* Wv = (const float*)d_in[3];
  const float* Wu = (const float*)d_in[4];
  const float* bu = (const float*)d_in[5];
  float* out = (float*)d_out;

  char* ws = (char*)d_ws;
  const size_t MB = 1u << 20;
  short* xb  = (short*)(ws + 0 * MB);    // x bf16; dead after gemm_qkv
  short* qf  = (short*)(ws + 0 * MB);    // Q frags overlay xb
  short* qb  = (short*)(ws + 16 * MB);   // Q rows; dead after frag_qk
  short* vfb = (short*)(ws + 16 * MB);   // V frags overlay qb
  short* kb  = (short*)(ws + 32 * MB);
  short* vb  = (short*)(ws + 48 * MB);
  short* kfb = (short*)(ws + 64 * MB);
  short* ob  = (short*)(ws + 80 * MB);
  short* wqb = (short*)(ws + 96 * MB);
  short* wkb = (short*)(ws + 98 * MB);
  short* wvb = (short*)(ws + 100 * MB);
  short* wub = (short*)(ws + 102 * MB);

  cast_kernel<<<4096, 256, 0, stream>>>(x, xb, 8388608);
  cast4_kernel<<<dim3(512, 4), 256, 0, stream>>>(Wq, Wk, Wv, Wu, wqb, wkb, wvb, wub);

  gemm_qkv_kernel<<<dim3(64, 8, 3), 256, 0, stream>>>(xb, wqb, wkb, wvb, qb, kb, vb);
  frag_qk_kernel<<<dim3(64, 64), 256, 0, stream>>>(qb, kb, qf, kfb);
  frag_v_kernel<<<dim3(64, 64), 256, 0, stream>>>(vb, vfb);
  attn_kernel<<<512, 256, 0, stream>>>(qf, kfb, vfb, ob);
  gemm_out_kernel<<<dim3(64, 8), 256, 0, stream>>>(ob, wub, bu, out);
}

// Round 9
// 211.086 us; speedup vs baseline: 1.0012x; 1.0012x over previous
//
#include <hip/hip_runtime.h>
#include <stdint.h>
#include <math.h>

// Problem: B=4, S=2048, E=1024, H=16, D=64
// d_in order (setup_inputs dict): x, Wk, Wq, Wv, Wu, bu   (note Wk before Wq!)

typedef __attribute__((ext_vector_type(8))) short bf16x8;
typedef __attribute__((ext_vector_type(4))) float f32x4;
typedef __attribute__((ext_vector_type(16))) float f32x16;
typedef __attribute__((ext_vector_type(4))) int i32x4;
typedef __attribute__((ext_vector_type(4))) short s16x4;

#define GLOAD_LDS16(gp, lp)                                                     \
  __builtin_amdgcn_global_load_lds(                                             \
      (__attribute__((address_space(1))) void*)(gp),                            \
      (__attribute__((address_space(3))) void*)(lp), 16, 0, 0)

#define WAITVM(N) asm volatile("s_waitcnt vmcnt(" #N ")" ::: "memory")

__device__ __forceinline__ short f2bf(float f) {
  union { float f; uint32_t u; } v; v.f = f;
  uint32_t r = v.u + 0x7FFFu + ((v.u >> 16) & 1u);  // RNE
  return (short)(r >> 16);
}
__device__ __forceinline__ float bf2f(short s) {
  union { uint32_t u; float f; } v; v.u = ((uint32_t)(uint16_t)s) << 16;
  return v.f;
}
__device__ __forceinline__ short f2bfn(float f) {
  union { __bf16 h; short s; } u; u.h = (__bf16)f; return u.s;
}
__device__ __forceinline__ uint32_t pk2n(float a, float b) {
  union { __bf16 h[2]; uint32_t u; } v;
  v.h[0] = (__bf16)a; v.h[1] = (__bf16)b;
  return v.u;
}

// exchange across the lane<32 / lane>=32 split (T12)
__device__ __forceinline__ void swap32(uint32_t a, uint32_t b, int hi,
                                       uint32_t& out0, uint32_t& out1) {
#if __has_builtin(__builtin_amdgcn_permlane32_swap)
  typedef __attribute__((ext_vector_type(2))) int i32x2;
  i32x2 r = __builtin_amdgcn_permlane32_swap((int)a, (int)b, false, false);
  out0 = (uint32_t)r.x; out1 = (uint32_t)r.y;
#else
  uint32_t ta = (uint32_t)__shfl_xor((int)a, 32);
  uint32_t tb = (uint32_t)__shfl_xor((int)b, 32);
  out0 = hi ? tb : a;
  out1 = hi ? b : ta;
#endif
}

// ---------------- cast fp32 -> bf16, vectorized (G13) ----------------
__global__ __launch_bounds__(256) void cast_kernel(const float* __restrict__ src,
                                                   short* __restrict__ dst, int n) {
  int i = (blockIdx.x * 256 + threadIdx.x) * 8;
  if (i >= n) return;
  const float4* s = (const float4*)(src + i);
  float4 f0 = s[0], f1 = s[1];
  bf16x8 o;
  o[0] = f2bf(f0.x); o[1] = f2bf(f0.y); o[2] = f2bf(f0.z); o[3] = f2bf(f0.w);
  o[4] = f2bf(f1.x); o[5] = f2bf(f1.y); o[6] = f2bf(f1.z); o[7] = f2bf(f1.w);
  *(bf16x8*)(dst + i) = o;
}

__global__ __launch_bounds__(256) void cast4_kernel(const float* __restrict__ w0,
                                                    const float* __restrict__ w1,
                                                    const float* __restrict__ w2,
                                                    const float* __restrict__ w3,
                                                    short* o0, short* o1, short* o2, short* o3) {
  const float* src = (blockIdx.y == 0) ? w0 : (blockIdx.y == 1) ? w1 : (blockIdx.y == 2) ? w2 : w3;
  short* dst = (blockIdx.y == 0) ? o0 : (blockIdx.y == 1) ? o1 : (blockIdx.y == 2) ? o2 : o3;
  int i = (blockIdx.x * 256 + threadIdx.x) * 8;
  const float4* s = (const float4*)(src + i);
  float4 f0 = s[0], f1 = s[1];
  bf16x8 o;
  o[0] = f2bf(f0.x); o[1] = f2bf(f0.y); o[2] = f2bf(f0.z); o[3] = f2bf(f0.w);
  o[4] = f2bf(f1.x); o[5] = f2bf(f1.y); o[6] = f2bf(f1.z); o[7] = f2bf(f1.w);
  *(bf16x8*)(dst + i) = o;
}

// ---------------- B^T GEMM (m97 structure): C[i,j] = sum_k A[i,k]*B[j,k] ----
template <bool F32OUT>
__device__ __forceinline__ void gemm_bt_core(const short* __restrict__ A,
                                             const short* __restrict__ Bm,
                                             short* __restrict__ Cb,
                                             float* __restrict__ Cf,
                                             const float* __restrict__ bias) {
  __shared__ short a_lds[128 * 64];
  __shared__ short b_lds[128 * 64];
  const int tid = threadIdx.x;
  const int w = tid >> 6, l = tid & 63;
  const int l15 = l & 15, lhi = l >> 4;
  const int wr = w >> 1, wc = w & 1;
  const int row0 = blockIdx.x * 128;
  const int col0 = blockIdx.y * 128;

  f32x4 acc[4][4];
#pragma unroll
  for (int m = 0; m < 4; ++m)
#pragma unroll
    for (int n = 0; n < 4; ++n)
      acc[m][n] = (f32x4){0.f, 0.f, 0.f, 0.f};

  const int o0 = tid * 16;
  const int sr = o0 >> 7;
  const int sc = o0 & 127;

  for (int kt = 0; kt < 16; ++kt) {
    const char* Ab = (const char*)A + (size_t)(row0 + sr) * 2048 + kt * 128 + sc;
    const char* Bb = (const char*)Bm + (size_t)(col0 + sr) * 2048 + kt * 128 + sc;
#pragma unroll
    for (int i = 0; i < 4; ++i) {
      GLOAD_LDS16(Ab + (size_t)i * 32 * 2048, (char*)a_lds + i * 4096 + o0);
      GLOAD_LDS16(Bb + (size_t)i * 32 * 2048, (char*)b_lds + i * 4096 + o0);
    }
    __syncthreads();
#pragma unroll
    for (int kk = 0; kk < 2; ++kk) {
      bf16x8 af[4], bg[4];
#pragma unroll
      for (int m = 0; m < 4; ++m) {
        int r = wr * 64 + m * 16 + l15;
        af[m] = *(const bf16x8*)((const char*)a_lds + r * 128 + kk * 64 + lhi * 16);
      }
#pragma unroll
      for (int n = 0; n < 4; ++n) {
        int r = wc * 64 + n * 16 + l15;
        bg[n] = *(const bf16x8*)((const char*)b_lds + r * 128 + kk * 64 + lhi * 16);
      }
#pragma unroll
      for (int m = 0; m < 4; ++m)
#pragma unroll
        for (int n = 0; n < 4; ++n)
          acc[m][n] = __builtin_amdgcn_mfma_f32_16x16x32_bf16(af[m], bg[n], acc[m][n], 0, 0, 0);
    }
    __syncthreads();
  }

#pragma unroll
  for (int m = 0; m < 4; ++m) {
#pragma unroll
    for (int n = 0; n < 4; ++n) {
      int colg = col0 + wc * 64 + n * 16 + l15;
#pragma unroll
      for (int r = 0; r < 4; ++r) {
        int rowg = row0 + wr * 64 + m * 16 + lhi * 4 + r;
        float v = acc[m][n][r];
        if constexpr (F32OUT) {
          Cf[(size_t)rowg * 1024 + colg] = v + bias[colg];
        } else {
          Cb[(size_t)rowg * 1024 + colg] = f2bfn(v);
        }
      }
    }
  }
}

__global__ __launch_bounds__(256) void gemm_qkv_kernel(const short* __restrict__ xb,
                                                       const short* __restrict__ wq,
                                                       const short* __restrict__ wk,
                                                       const short* __restrict__ wv,
                                                       short* qo, short* ko, short* vo) {
  const short* Bm = (blockIdx.z == 0) ? wq : (blockIdx.z == 1) ? wk : wv;
  short* C = (blockIdx.z == 0) ? qo : (blockIdx.z == 1) ? ko : vo;
  gemm_bt_core<false>(xb, Bm, C, nullptr, nullptr);
}

__global__ __launch_bounds__(256) void gemm_out_kernel(const short* __restrict__ ob,
                                                       const short* __restrict__ wu,
                                                       const float* __restrict__ bias,
                                                       float* __restrict__ out) {
  gemm_bt_core<true>(ob, wu, nullptr, out, bias);
}

// ---------------- fragmentize Q,K: [bh][t32][s][lane][8] -------------------
__global__ __launch_bounds__(256) void frag_qk_kernel(const short* __restrict__ qb,
                                                      const short* __restrict__ kb,
                                                      short* __restrict__ qf,
                                                      short* __restrict__ kf) {
  int t = blockIdx.x, bh = blockIdx.y;
  int b = bh >> 4, h = bh & 15;
  __shared__ short q_t[32][72], k_t[32][72];
  int tid = threadIdx.x;
  int row = tid >> 3, seg = tid & 7;
  size_t src = ((size_t)(b * 2048 + t * 32 + row)) * 1024 + h * 64 + seg * 8;
  *(bf16x8*)&q_t[row][seg * 8] = *(const bf16x8*)(qb + src);
  *(bf16x8*)&k_t[row][seg * 8] = *(const bf16x8*)(kb + src);
  __syncthreads();
  int s = tid >> 6, l = tid & 63, l31 = l & 31, hi = l >> 5;
  bf16x8 cq = *(const bf16x8*)&q_t[l31][hi * 8 + s * 16];
  bf16x8 ck = *(const bf16x8*)&k_t[l31][hi * 8 + s * 16];
  size_t dst = ((size_t)bh * 64 + t) * 2048 + s * 512 + l * 8;
  *(bf16x8*)(qf + dst) = cq;
  *(bf16x8*)(kf + dst) = ck;
}

// ---------------- fragmentize V (transposed): [bh][t32][u][lane][8] --------
__global__ __launch_bounds__(256) void frag_v_kernel(const short* __restrict__ vb,
                                                     short* __restrict__ vf) {
  int t = blockIdx.x, bh = blockIdx.y;
  int b = bh >> 4, h = bh & 15;
  __shared__ short v_t[32][72];
  int tid = threadIdx.x;
  int row = tid >> 3, seg = tid & 7;
  *(bf16x8*)&v_t[row][seg * 8] =
      *(const bf16x8*)(vb + ((size_t)(b * 2048 + t * 32 + row)) * 1024 + h * 64 + seg * 8);
  __syncthreads();
  int u = tid >> 6, l = tid & 63, l31 = l & 31, hi = l >> 5;
  int dblk = u >> 1, koff = u & 1;
  bf16x8 c;
#pragma unroll
  for (int j = 0; j < 8; ++j) c[j] = v_t[koff * 16 + hi * 8 + j][dblk * 32 + l31];
  *(bf16x8*)(vf + ((size_t)bh * 64 + t) * 2048 + u * 512 + l * 8) = c;
}

// ---------------- causal flash attention v9 ---------------------------------
// grid 512 (8 pairs x 64 bh), 512 thr (8 waves = 4 q-strips x 2 k-half teams).
// Block does 128-row q-tile j then 15-j (equal 34 k-tiles). Both teams share
// each staged 64-k tile; team t computes k-sub-block [32t,32t+32). Fixed-m
// softmax (m=8 baked into MFMA C-init): no max tracking, no rescale; row-sum
// accumulated via ones-MFMA on the idle matrix pipe. Team merge = pure add.
__global__ __launch_bounds__(512) void attn_kernel(const short* __restrict__ qf,
                                                   const short* __restrict__ kf,
                                                   const short* __restrict__ vf,
                                                   short* __restrict__ ob) {
  const float QSCALE = 0.03125f * 1.44269504f;  // (E^-0.25)^2 * log2(e)
  int id = blockIdx.x;
  int p = id >> 6;             // pair index 0..7
  int bh = id & 63;            // id%8 == bh%8 -> bh stays on one XCD
  int b = bh >> 4, h = bh & 15;
  int tid = threadIdx.x;
  int wid = tid >> 6, l = tid & 63;
  int l31 = l & 31, hi = l >> 5;
  int qs = wid & 3, team = wid >> 2;

  __shared__ short kbuf[2][4096];          // 8KB per 64-k K-tile (frag order)
  __shared__ short vbuf[2][4096];
  __shared__ float mrg[4][64][34];         // [strip][lane][o_lo16 o_hi16 lsum]

  const short* qfb = qf + (size_t)bh * 131072;
  const short* kfb = kf + (size_t)bh * 131072;
  const short* vfb = vf + (size_t)bh * 131072;

  bf16x8 ones;
#pragma unroll
  for (int j = 0; j < 8; ++j) ones[j] = (short)0x3F80;  // bf16 1.0

#define STAGE(t, bi) do {                                                  \
    GLOAD_LDS16(kfb + (size_t)(t) * 4096 + tid * 8,                        \
                (char*)&kbuf[bi][0] + tid * 16);                           \
    GLOAD_LDS16(vfb + (size_t)(t) * 4096 + tid * 8,                        \
                (char*)&vbuf[bi][0] + tid * 16);                           \
  } while (0)

  for (int part = 0; part < 2; ++part) {
    int j = part ? (15 - p) : p;   // 128-row q-tile index 0..15
    int qt = 4 * j + qs;           // 32-row strip
    int qrow0 = qt * 32;
    int qg = qrow0 + l31;
    int qmax = qrow0 + 31;
    int nk = 2 * (j + 1);          // 64-k tiles (>= 2)

    // Q fragments, pre-scaled
    bf16x8 aq[4];
    {
      const short* qp = qfb + qt * 2048 + l * 8;
#pragma unroll
      for (int s = 0; s < 4; ++s) {
        bf16x8 t = *(const bf16x8*)(qp + s * 512);
#pragma unroll
        for (int jj = 0; jj < 8; ++jj) t[jj] = f2bfn(bf2f(t[jj]) * QSCALE);
        aq[s] = t;
      }
    }

    f32x16 o_lo = {}, o_hi = {}, o_sum = {};

    STAGE(0, 0);
    STAGE(1, 1);
    WAITVM(2);                       // tile 0 landed (tile 1 in flight)
    __builtin_amdgcn_s_barrier();
    __builtin_amdgcn_sched_barrier(0);

    for (int t = 0; t < nk; ++t) {
      int cur = t & 1;
      int k0w = t * 64 + team * 32;  // this wave's 32-k sub-block
      if (k0w <= qmax) {
        const char* kb_ = (const char*)&kbuf[cur][0] + team * 4096;
        const char* vb_ = (const char*)&vbuf[cur][0] + team * 4096;
        f32x16 st;
#pragma unroll
        for (int r = 0; r < 16; ++r) st[r] = -8.0f;   // fixed-m C-init
#pragma unroll
        for (int s = 0; s < 4; ++s) {
          bf16x8 ak = *(const bf16x8*)(kb_ + (s * 64 + l) * 16);
          st = __builtin_amdgcn_mfma_f32_32x32x16_bf16(ak, aq[s], st, 0, 0, 0);
        }

        if (k0w + 31 > qrow0) {        // diagonal sub-block: mask k > q
#pragma unroll
          for (int r = 0; r < 16; ++r) {
            int kk = k0w + (r & 3) + 8 * (r >> 2) + 4 * hi;
            if (kk > qg) st[r] = -INFINITY;
          }
        }

        // P = exp2(score - 8)  (subtraction pre-baked into C-init)
#pragma unroll
        for (int r = 0; r < 16; ++r) st[r] = exp2f(st[r]);

        // T12 pack: P -> bf16 A-fragments
        uint32_t a0, a2, b1, b3, c0, c2, d1, d3;
        swap32(pk2n(st[0], st[1]),   pk2n(st[4], st[5]),   hi, a0, a2);
        swap32(pk2n(st[2], st[3]),   pk2n(st[6], st[7]),   hi, b1, b3);
        swap32(pk2n(st[8], st[9]),   pk2n(st[12], st[13]), hi, c0, c2);
        swap32(pk2n(st[10], st[11]), pk2n(st[14], st[15]), hi, d1, d3);
        i32x4 u0 = {(int)a0, (int)b1, (int)a2, (int)b3};
        i32x4 u1 = {(int)c0, (int)d1, (int)c2, (int)d3};
        bf16x8 pa0 = __builtin_bit_cast(bf16x8, u0);
        bf16x8 pa1 = __builtin_bit_cast(bf16x8, u1);

        // PV + row-sum on the MFMA pipe
        bf16x8 av;
        av = *(const bf16x8*)(vb_ + (0 * 64 + l) * 16);
        o_lo = __builtin_amdgcn_mfma_f32_32x32x16_bf16(av, pa0, o_lo, 0, 0, 0);
        av = *(const bf16x8*)(vb_ + (1 * 64 + l) * 16);
        o_lo = __builtin_amdgcn_mfma_f32_32x32x16_bf16(av, pa1, o_lo, 0, 0, 0);
        av = *(const bf16x8*)(vb_ + (2 * 64 + l) * 16);
        o_hi = __builtin_amdgcn_mfma_f32_32x32x16_bf16(av, pa0, o_hi, 0, 0, 0);
        av = *(const bf16x8*)(vb_ + (3 * 64 + l) * 16);
        o_hi = __builtin_amdgcn_mfma_f32_32x32x16_bf16(av, pa1, o_hi, 0, 0, 0);
        o_sum = __builtin_amdgcn_mfma_f32_32x32x16_bf16(ones, pa0, o_sum, 0, 0, 0);
        o_sum = __builtin_amdgcn_mfma_f32_32x32x16_bf16(ones, pa1, o_sum, 0, 0, 0);
      }
      __builtin_amdgcn_s_barrier();          // all waves done reading buf[cur]
      __builtin_amdgcn_sched_barrier(0);
      if (t + 2 < nk) {
        STAGE(t + 2, cur);
        WAITVM(2);                           // tile t+1's loads complete
      } else {
        WAITVM(0);
      }
      __builtin_amdgcn_s_barrier();          // tile t+1 visible to all waves
      __builtin_amdgcn_sched_barrier(0);
    }

    // team merge (same fixed m -> pure addition)
    float lsum = o_sum[0];
    if (team == 1) {
      float* pp = &mrg[qs][l][0];
#pragma unroll
      for (int r = 0; r < 16; ++r) { pp[r] = o_lo[r]; pp[16 + r] = o_hi[r]; }
      pp[32] = lsum;
    }
    __syncthreads();
    if (team == 0) {
      const float* pp = &mrg[qs][l][0];
      float inv = 1.0f / (lsum + pp[32]);
      short* obase = ob + (size_t)(b * 2048 + qg) * 1024 + h * 64;
#pragma unroll
      for (int g = 0; g < 4; ++g) {
        int d0 = 8 * g + 4 * hi;
        s16x4 v0, v1;
#pragma unroll
        for (int jj = 0; jj < 4; ++jj) {
          v0[jj] = f2bfn((o_lo[4 * g + jj] + pp[4 * g + jj]) * inv);
          v1[jj] = f2bfn((o_hi[4 * g + jj] + pp[16 + 4 * g + jj]) * inv);
        }
        *(s16x4*)(obase + d0) = v0;
        *(s16x4*)(obase + 32 + d0) = v1;
      }
    }
    __syncthreads();   // mrg safe for reuse; align teams before next part
  }
#undef STAGE
}

extern "C" void kernel_launch(void* const* d_in, const int* in_sizes, int n_in,
                              void* d_out, int out_size, void* d_ws, size_t ws_size,
                              hipStream_t stream) {
  const float* x  = (const float*)d_in[0];
  const float* Wk = (const float*)d_in[1];
  const float* Wq = (const float*)d_in[2];
  const float* Wv = (const float*)d_in[3];
  const float* Wu = (const float*)d_in[4];
  const float* bu = (const float*)d_in[5];
  float* out = (float*)d_out;

  char* ws = (char*)d_ws;
  const size_t MB = 1u << 20;
  short* xb  = (short*)(ws + 0 * MB);    // x bf16; dead after gemm_qkv
  short* qf  = (short*)(ws + 0 * MB);    // Q frags overlay xb
  short* qb  = (short*)(ws + 16 * MB);   // Q rows; dead after frag_qk
  short* vfb = (short*)(ws + 16 * MB);   // V frags overlay qb
  short* kb  = (short*)(ws + 32 * MB);
  short* vb  = (short*)(ws + 48 * MB);
  short* kfb = (short*)(ws + 64 * MB);
  short* ob  = (short*)(ws + 80 * MB);
  short* wqb = (short*)(ws + 96 * MB);
  short* wkb = (short*)(ws + 98 * MB);
  short* wvb = (short*)(ws + 100 * MB);
  short* wub = (short*)(ws + 102 * MB);

  cast_kernel<<<4096, 256, 0, stream>>>(x, xb, 8388608);
  cast4_kernel<<<dim3(512, 4), 256, 0, stream>>>(Wq, Wk, Wv, Wu, wqb, wkb, wvb, wub);

  gemm_qkv_kernel<<<dim3(64, 8, 3), 256, 0, stream>>>(xb, wqb, wkb, wvb, qb, kb, vb);
  frag_qk_kernel<<<dim3(64, 64), 256, 0, stream>>>(qb, kb, qf, kfb);
  frag_v_kernel<<<dim3(64, 64), 256, 0, stream>>>(vb, vfb);
  attn_kernel<<<512, 512, 0, stream>>>(qf, kfb, vfb, ob);
  gemm_out_kernel<<<dim3(64, 8), 256, 0, stream>>>(ob, wub, bu, out);
}

// Round 10
// 198.275 us; speedup vs baseline: 1.0659x; 1.0646x over previous
//
#include <hip/hip_runtime.h>
#include <stdint.h>
#include <math.h>

// Problem: B=4, S=2048, E=1024, H=16, D=64
// d_in order (setup_inputs dict): x, Wk, Wq, Wv, Wu, bu   (note Wk before Wq!)

typedef __attribute__((ext_vector_type(8))) short bf16x8;
typedef __attribute__((ext_vector_type(4))) float f32x4;
typedef __attribute__((ext_vector_type(16))) float f32x16;
typedef __attribute__((ext_vector_type(4))) int i32x4;
typedef __attribute__((ext_vector_type(4))) short s16x4;

#define GLOAD_LDS16(gp, lp)                                                     \
  __builtin_amdgcn_global_load_lds(                                             \
      (__attribute__((address_space(1))) void*)(gp),                            \
      (__attribute__((address_space(3))) void*)(lp), 16, 0, 0)

__device__ __forceinline__ short f2bf(float f) {
  union { float f; uint32_t u; } v; v.f = f;
  uint32_t r = v.u + 0x7FFFu + ((v.u >> 16) & 1u);  // RNE
  return (short)(r >> 16);
}
__device__ __forceinline__ float bf2f(short s) {
  union { uint32_t u; float f; } v; v.u = ((uint32_t)(uint16_t)s) << 16;
  return v.f;
}
__device__ __forceinline__ short f2bfn(float f) {
  union { __bf16 h; short s; } u; u.h = (__bf16)f; return u.s;
}
__device__ __forceinline__ uint32_t pk2n(float a, float b) {
  union { __bf16 h[2]; uint32_t u; } v;
  v.h[0] = (__bf16)a; v.h[1] = (__bf16)b;
  return v.u;
}

// exchange across the lane<32 / lane>=32 split (T12)
__device__ __forceinline__ void swap32(uint32_t a, uint32_t b, int hi,
                                       uint32_t& out0, uint32_t& out1) {
#if __has_builtin(__builtin_amdgcn_permlane32_swap)
  typedef __attribute__((ext_vector_type(2))) int i32x2;
  i32x2 r = __builtin_amdgcn_permlane32_swap((int)a, (int)b, false, false);
  out0 = (uint32_t)r.x; out1 = (uint32_t)r.y;
#else
  uint32_t ta = (uint32_t)__shfl_xor((int)a, 32);
  uint32_t tb = (uint32_t)__shfl_xor((int)b, 32);
  out0 = hi ? tb : a;
  out1 = hi ? b : ta;
#endif
}

// ---------------- cast fp32 -> bf16, vectorized (G13) ----------------
__global__ __launch_bounds__(256) void cast_kernel(const float* __restrict__ src,
                                                   short* __restrict__ dst, int n) {
  int i = (blockIdx.x * 256 + threadIdx.x) * 8;
  if (i >= n) return;
  const float4* s = (const float4*)(src + i);
  float4 f0 = s[0], f1 = s[1];
  bf16x8 o;
  o[0] = f2bf(f0.x); o[1] = f2bf(f0.y); o[2] = f2bf(f0.z); o[3] = f2bf(f0.w);
  o[4] = f2bf(f1.x); o[5] = f2bf(f1.y); o[6] = f2bf(f1.z); o[7] = f2bf(f1.w);
  *(bf16x8*)(dst + i) = o;
}

__global__ __launch_bounds__(256) void cast4_kernel(const float* __restrict__ w0,
                                                    const float* __restrict__ w1,
                                                    const float* __restrict__ w2,
                                                    const float* __restrict__ w3,
                                                    short* o0, short* o1, short* o2, short* o3) {
  const float* src = (blockIdx.y == 0) ? w0 : (blockIdx.y == 1) ? w1 : (blockIdx.y == 2) ? w2 : w3;
  short* dst = (blockIdx.y == 0) ? o0 : (blockIdx.y == 1) ? o1 : (blockIdx.y == 2) ? o2 : o3;
  int i = (blockIdx.x * 256 + threadIdx.x) * 8;
  const float4* s = (const float4*)(src + i);
  float4 f0 = s[0], f1 = s[1];
  bf16x8 o;
  o[0] = f2bf(f0.x); o[1] = f2bf(f0.y); o[2] = f2bf(f0.z); o[3] = f2bf(f0.w);
  o[4] = f2bf(f1.x); o[5] = f2bf(f1.y); o[6] = f2bf(f1.z); o[7] = f2bf(f1.w);
  *(bf16x8*)(dst + i) = o;
}

// ---------------- B^T GEMM (m97 structure): C[i,j] = sum_k A[i,k]*B[j,k] ----
template <bool F32OUT>
__device__ __forceinline__ void gemm_bt_core(const short* __restrict__ A,
                                             const short* __restrict__ Bm,
                                             short* __restrict__ Cb,
                                             float* __restrict__ Cf,
                                             const float* __restrict__ bias) {
  __shared__ short a_lds[128 * 64];
  __shared__ short b_lds[128 * 64];
  const int tid = threadIdx.x;
  const int w = tid >> 6, l = tid & 63;
  const int l15 = l & 15, lhi = l >> 4;
  const int wr = w >> 1, wc = w & 1;
  const int row0 = blockIdx.x * 128;
  const int col0 = blockIdx.y * 128;

  f32x4 acc[4][4];
#pragma unroll
  for (int m = 0; m < 4; ++m)
#pragma unroll
    for (int n = 0; n < 4; ++n)
      acc[m][n] = (f32x4){0.f, 0.f, 0.f, 0.f};

  const int o0 = tid * 16;
  const int sr = o0 >> 7;
  const int sc = o0 & 127;

  for (int kt = 0; kt < 16; ++kt) {
    const char* Ab = (const char*)A + (size_t)(row0 + sr) * 2048 + kt * 128 + sc;
    const char* Bb = (const char*)Bm + (size_t)(col0 + sr) * 2048 + kt * 128 + sc;
#pragma unroll
    for (int i = 0; i < 4; ++i) {
      GLOAD_LDS16(Ab + (size_t)i * 32 * 2048, (char*)a_lds + i * 4096 + o0);
      GLOAD_LDS16(Bb + (size_t)i * 32 * 2048, (char*)b_lds + i * 4096 + o0);
    }
    __syncthreads();
#pragma unroll
    for (int kk = 0; kk < 2; ++kk) {
      bf16x8 af[4], bg[4];
#pragma unroll
      for (int m = 0; m < 4; ++m) {
        int r = wr * 64 + m * 16 + l15;
        af[m] = *(const bf16x8*)((const char*)a_lds + r * 128 + kk * 64 + lhi * 16);
      }
#pragma unroll
      for (int n = 0; n < 4; ++n) {
        int r = wc * 64 + n * 16 + l15;
        bg[n] = *(const bf16x8*)((const char*)b_lds + r * 128 + kk * 64 + lhi * 16);
      }
#pragma unroll
      for (int m = 0; m < 4; ++m)
#pragma unroll
        for (int n = 0; n < 4; ++n)
          acc[m][n] = __builtin_amdgcn_mfma_f32_16x16x32_bf16(af[m], bg[n], acc[m][n], 0, 0, 0);
    }
    __syncthreads();
  }

#pragma unroll
  for (int m = 0; m < 4; ++m) {
#pragma unroll
    for (int n = 0; n < 4; ++n) {
      int colg = col0 + wc * 64 + n * 16 + l15;
#pragma unroll
      for (int r = 0; r < 4; ++r) {
        int rowg = row0 + wr * 64 + m * 16 + lhi * 4 + r;
        float v = acc[m][n][r];
        if constexpr (F32OUT) {
          Cf[(size_t)rowg * 1024 + colg] = v + bias[colg];
        } else {
          Cb[(size_t)rowg * 1024 + colg] = f2bfn(v);
        }
      }
    }
  }
}

__global__ __launch_bounds__(256) void gemm_qkv_kernel(const short* __restrict__ xb,
                                                       const short* __restrict__ wq,
                                                       const short* __restrict__ wk,
                                                       const short* __restrict__ wv,
                                                       short* qo, short* ko, short* vo) {
  const short* Bm = (blockIdx.z == 0) ? wq : (blockIdx.z == 1) ? wk : wv;
  short* C = (blockIdx.z == 0) ? qo : (blockIdx.z == 1) ? ko : vo;
  gemm_bt_core<false>(xb, Bm, C, nullptr, nullptr);
}

__global__ __launch_bounds__(256) void gemm_out_kernel(const short* __restrict__ ob,
                                                       const short* __restrict__ wu,
                                                       const float* __restrict__ bias,
                                                       float* __restrict__ out) {
  gemm_bt_core<true>(ob, wu, nullptr, out, bias);
}

// ---------------- fragmentize Q,K: [bh][t32][s][lane][8] -------------------
__global__ __launch_bounds__(256) void frag_qk_kernel(const short* __restrict__ qb,
                                                      const short* __restrict__ kb,
                                                      short* __restrict__ qf,
                                                      short* __restrict__ kf) {
  int t = blockIdx.x, bh = blockIdx.y;
  int b = bh >> 4, h = bh & 15;
  __shared__ short q_t[32][72], k_t[32][72];
  int tid = threadIdx.x;
  int row = tid >> 3, seg = tid & 7;
  size_t src = ((size_t)(b * 2048 + t * 32 + row)) * 1024 + h * 64 + seg * 8;
  *(bf16x8*)&q_t[row][seg * 8] = *(const bf16x8*)(qb + src);
  *(bf16x8*)&k_t[row][seg * 8] = *(const bf16x8*)(kb + src);
  __syncthreads();
  int s = tid >> 6, l = tid & 63, l31 = l & 31, hi = l >> 5;
  bf16x8 cq = *(const bf16x8*)&q_t[l31][hi * 8 + s * 16];
  bf16x8 ck = *(const bf16x8*)&k_t[l31][hi * 8 + s * 16];
  size_t dst = ((size_t)bh * 64 + t) * 2048 + s * 512 + l * 8;
  *(bf16x8*)(qf + dst) = cq;
  *(bf16x8*)(kf + dst) = ck;
}

// ---------------- fragmentize V (transposed): [bh][t32][u][lane][8] --------
__global__ __launch_bounds__(256) void frag_v_kernel(const short* __restrict__ vb,
                                                     short* __restrict__ vf) {
  int t = blockIdx.x, bh = blockIdx.y;
  int b = bh >> 4, h = bh & 15;
  __shared__ short v_t[32][72];
  int tid = threadIdx.x;
  int row = tid >> 3, seg = tid & 7;
  *(bf16x8*)&v_t[row][seg * 8] =
      *(const bf16x8*)(vb + ((size_t)(b * 2048 + t * 32 + row)) * 1024 + h * 64 + seg * 8);
  __syncthreads();
  int u = tid >> 6, l = tid & 63, l31 = l & 31, hi = l >> 5;
  int dblk = u >> 1, koff = u & 1;
  bf16x8 c;
#pragma unroll
  for (int j = 0; j < 8; ++j) c[j] = v_t[koff * 16 + hi * 8 + j][dblk * 32 + l31];
  *(bf16x8*)(vf + ((size_t)bh * 64 + t) * 2048 + u * 512 + l * 8) = c;
}

// ---------------- causal flash attention v10: barrier-free dataflow ---------
// grid (bh=64, grp=8) x 512 thr (8 waves). Wave-job = (strip-pair, k-team):
// pair = grp*4 + (wid>>1), team = wid&1. Each wave independently processes
// strips (pair, 63-pair), its half of the causal k-range, reading K/V
// FRAGMENTS straight from L2 (lane-contiguous 1KB loads -- no LDS, no
// barriers in the loop, compiler free to software-pipeline). Fixed-m softmax
// (m=8 in MFMA C-init). Teams merge via LDS once per part (2 barriers total).
__global__ __launch_bounds__(512) void attn_kernel(const short* __restrict__ qf,
                                                   const short* __restrict__ kf,
                                                   const short* __restrict__ vf,
                                                   short* __restrict__ ob) {
  const float QSCALE = 0.03125f * 1.44269504f;  // (E^-0.25)^2 * log2(e)
  int bh = blockIdx.x;                 // linear id % 8 == bh % 8 -> XCD-affine
  int b = bh >> 4, h = bh & 15;
  int tid = threadIdx.x;
  int wid = tid >> 6, l = tid & 63;
  int l31 = l & 31, hi = l >> 5;
  int pair = blockIdx.y * 4 + (wid >> 1);  // 0..31
  int team = wid & 1;
  int slot = wid >> 1;                     // 0..3 (mrg slot per pair)

  __shared__ float mrg[4][64][34];         // [slot][lane][o_lo16 o_hi16 lsum]

  const short* qfb = qf + (size_t)bh * 131072;
  const short* kfb = kf + (size_t)bh * 131072;
  const short* vfb = vf + (size_t)bh * 131072;

  for (int part = 0; part < 2; ++part) {
    int sidx = part ? (63 - pair) : pair;  // 32-row strip index 0..63
    int qrow0 = sidx * 32;
    int qg = qrow0 + l31;
    int n = sidx + 1;                      // causal 32-k tiles
    int t0 = team ? (n >> 1) : 0;          // team1 gets upper half (diagonal)
    int t1 = team ? n : (n >> 1);

    // Q fragments (lane-contiguous), pre-scaled
    bf16x8 aq[4];
    {
      const short* qp = qfb + sidx * 2048 + l * 8;
#pragma unroll
      for (int s = 0; s < 4; ++s) {
        bf16x8 t = *(const bf16x8*)(qp + s * 512);
#pragma unroll
        for (int jj = 0; jj < 8; ++jj) t[jj] = f2bfn(bf2f(t[jj]) * QSCALE);
        aq[s] = t;
      }
    }

    f32x16 o_lo = {}, o_hi = {};
    float lsum = 0.f;

    for (int t = t0; t < t1; ++t) {
      const short* kp = kfb + (size_t)t * 2048 + l * 8;
      const short* vp = vfb + (size_t)t * 2048 + l * 8;
      f32x16 st;
#pragma unroll
      for (int r = 0; r < 16; ++r) st[r] = -8.0f;   // fixed-m C-init
#pragma unroll
      for (int s = 0; s < 4; ++s) {
        bf16x8 ak = *(const bf16x8*)(kp + s * 512);
        st = __builtin_amdgcn_mfma_f32_32x32x16_bf16(ak, aq[s], st, 0, 0, 0);
      }

      if (t == sidx) {                     // diagonal tile: mask k > q
#pragma unroll
        for (int r = 0; r < 16; ++r) {
          int kk = qrow0 + (r & 3) + 8 * (r >> 2) + 4 * hi;
          if (kk > qg) st[r] = -INFINITY;
        }
      }

      // P = exp2(score - 8)
#pragma unroll
      for (int r = 0; r < 16; ++r) st[r] = exp2f(st[r]);

      // row-sum tree (lane half; partner half merged once per part)
      float sm[8];
#pragma unroll
      for (int r = 0; r < 8; ++r) sm[r] = st[r] + st[r + 8];
#pragma unroll
      for (int r = 0; r < 4; ++r) sm[r] += sm[r + 4];
      lsum += (sm[0] + sm[1]) + (sm[2] + sm[3]);

      // T12 pack: P -> bf16 A-fragments
      uint32_t a0, a2, b1, b3, c0, c2, d1, d3;
      swap32(pk2n(st[0], st[1]),   pk2n(st[4], st[5]),   hi, a0, a2);
      swap32(pk2n(st[2], st[3]),   pk2n(st[6], st[7]),   hi, b1, b3);
      swap32(pk2n(st[8], st[9]),   pk2n(st[12], st[13]), hi, c0, c2);
      swap32(pk2n(st[10], st[11]), pk2n(st[14], st[15]), hi, d1, d3);
      i32x4 u0 = {(int)a0, (int)b1, (int)a2, (int)b3};
      i32x4 u1 = {(int)c0, (int)d1, (int)c2, (int)d3};
      bf16x8 pa0 = __builtin_bit_cast(bf16x8, u0);
      bf16x8 pa1 = __builtin_bit_cast(bf16x8, u1);

      // PV from V fragments (lane-contiguous loads)
      bf16x8 av;
      av = *(const bf16x8*)(vp);
      o_lo = __builtin_amdgcn_mfma_f32_32x32x16_bf16(av, pa0, o_lo, 0, 0, 0);
      av = *(const bf16x8*)(vp + 512);
      o_lo = __builtin_amdgcn_mfma_f32_32x32x16_bf16(av, pa1, o_lo, 0, 0, 0);
      av = *(const bf16x8*)(vp + 1024);
      o_hi = __builtin_amdgcn_mfma_f32_32x32x16_bf16(av, pa0, o_hi, 0, 0, 0);
      av = *(const bf16x8*)(vp + 1536);
      o_hi = __builtin_amdgcn_mfma_f32_32x32x16_bf16(av, pa1, o_hi, 0, 0, 0);
    }

    lsum += __shfl_xor(lsum, 32);          // both k-halves of this team's range

    if (team == 1) {
      float* pp = &mrg[slot][l][0];
#pragma unroll
      for (int r = 0; r < 16; ++r) { pp[r] = o_lo[r]; pp[16 + r] = o_hi[r]; }
      pp[32] = lsum;
    }
    __syncthreads();
    if (team == 0) {
      const float* pp = &mrg[slot][l][0];
      float inv = 1.0f / (lsum + pp[32]);  // fixed m -> pure addition
      short* obase = ob + (size_t)(b * 2048 + qg) * 1024 + h * 64;
#pragma unroll
      for (int g = 0; g < 4; ++g) {
        int d0 = 8 * g + 4 * hi;
        s16x4 v0, v1;
#pragma unroll
        for (int jj = 0; jj < 4; ++jj) {
          v0[jj] = f2bfn((o_lo[4 * g + jj] + pp[4 * g + jj]) * inv);
          v1[jj] = f2bfn((o_hi[4 * g + jj] + pp[16 + 4 * g + jj]) * inv);
        }
        *(s16x4*)(obase + d0) = v0;
        *(s16x4*)(obase + 32 + d0) = v1;
      }
    }
    __syncthreads();   // mrg safe for reuse in part 1
  }
}

extern "C" void kernel_launch(void* const* d_in, const int* in_sizes, int n_in,
                              void* d_out, int out_size, void* d_ws, size_t ws_size,
                              hipStream_t stream) {
  const float* x  = (const float*)d_in[0];
  const float* Wk = (const float*)d_in[1];
  const float* Wq = (const float*)d_in[2];
  const float* Wv = (const float*)d_in[3];
  const float* Wu = (const float*)d_in[4];
  const float* bu = (const float*)d_in[5];
  float* out = (float*)d_out;

  char* ws = (char*)d_ws;
  const size_t MB = 1u << 20;
  short* xb  = (short*)(ws + 0 * MB);    // x bf16; dead after gemm_qkv
  short* qf  = (short*)(ws + 0 * MB);    // Q frags overlay xb
  short* qb  = (short*)(ws + 16 * MB);   // Q rows; dead after frag_qk
  short* vfb = (short*)(ws + 16 * MB);   // V frags overlay qb
  short* kb  = (short*)(ws + 32 * MB);
  short* vb  = (short*)(ws + 48 * MB);
  short* kfb = (short*)(ws + 64 * MB);
  short* ob  = (short*)(ws + 80 * MB);
  short* wqb = (short*)(ws + 96 * MB);
  short* wkb = (short*)(ws + 98 * MB);
  short* wvb = (short*)(ws + 100 * MB);
  short* wub = (short*)(ws + 102 * MB);

  cast_kernel<<<4096, 256, 0, stream>>>(x, xb, 8388608);
  cast4_kernel<<<dim3(512, 4), 256, 0, stream>>>(Wq, Wk, Wv, Wu, wqb, wkb, wvb, wub);

  gemm_qkv_kernel<<<dim3(64, 8, 3), 256, 0, stream>>>(xb, wqb, wkb, wvb, qb, kb, vb);
  frag_qk_kernel<<<dim3(64, 64), 256, 0, stream>>>(qb, kb, qf, kfb);
  frag_v_kernel<<<dim3(64, 64), 256, 0, stream>>>(vb, vfb);
  attn_kernel<<<dim3(64, 8), 512, 0, stream>>>(qf, kfb, vfb, ob);
  gemm_out_kernel<<<dim3(64, 8), 256, 0, stream>>>(ob, wub, bu, out);
}